// Round 8
// baseline (157.025 us; speedup 1.0000x reference)
//
#include <hip/hip_runtime.h>
#include <hip/hip_bf16.h>

typedef unsigned short u16;
typedef __attribute__((ext_vector_type(4))) float f32x4;
typedef __attribute__((ext_vector_type(8))) short s16x8;
typedef __attribute__((ext_vector_type(4))) unsigned short u16x4;

// ---------- helpers ----------
__device__ __forceinline__ u16 f2bf(float f) {
    union { float f; unsigned u; } v; v.f = f;
    unsigned r = v.u + 0x7fffu + ((v.u >> 16) & 1u);  // RNE (software)
    return (u16)(r >> 16);
}
__device__ __forceinline__ u16 f2bfh(float f) {   // hardware cvt via compiler
    __hip_bfloat16 h = __float2bfloat16(f);
    return *reinterpret_cast<u16*>(&h);
}
__device__ __forceinline__ float fexp2(float x) {
#if __has_builtin(__builtin_amdgcn_exp2f)
    return __builtin_amdgcn_exp2f(x);
#else
    return exp2f(x);
#endif
}
__device__ __forceinline__ void gload16(const void* g, void* lds_uniform) {
    __builtin_amdgcn_global_load_lds(
        (const __attribute__((address_space(1))) void*)g,
        (__attribute__((address_space(3))) void*)lds_uniform, 16, 0, 0);
}
__device__ __forceinline__ f32x4 mfma16(s16x8 a, s16x8 b, f32x4 c) {
    return __builtin_amdgcn_mfma_f32_16x16x32_bf16(a, b, c, 0, 0, 0);
}

// ---------- fused prep: cvt(q,k,v)->bf16 | weight transpose | mask packing ----------
// blocks [0,12288): convert; [12288,13312): wtrans; [13312,78848): packmask
__global__ void prep(const float4* __restrict__ q, const float4* __restrict__ k,
                     const float4* __restrict__ v, u16x4* __restrict__ qkv,
                     const float* __restrict__ Wq, const float* __restrict__ Wk,
                     const float* __restrict__ Wv, const float* __restrict__ Wo,
                     u16* __restrict__ WqT, u16* __restrict__ WkT,
                     u16* __restrict__ WvT, u16* __restrict__ WoT,
                     const int* __restrict__ mask, unsigned* __restrict__ bits) {
    __shared__ float tile[32][33];
    const int bid = blockIdx.x, tid = threadIdx.x;
    if (bid < 12288) {
        int i = bid * 256 + tid;               // 0 .. 3*2^20-1
        int sel = i >> 20, j = i & 0xFFFFF;
        const float4* in = (sel == 0) ? q : (sel == 1) ? k : v;
        float4 f = in[j];
        u16x4 o;
        o[0] = f2bf(f.x); o[1] = f2bf(f.y); o[2] = f2bf(f.z); o[3] = f2bf(f.w);
        qkv[i] = o;
    } else if (bid < 13312) {
        int idx = bid - 12288;
        int bz = idx >> 8, rem = idx & 255, by = rem >> 4, bx = rem & 15;
        const float* W; u16* T;
        switch (bz) {
            case 0: W = Wq; T = WqT; break;
            case 1: W = Wk; T = WkT; break;
            case 2: W = Wv; T = WvT; break;
            default: W = Wo; T = WoT; break;
        }
        const int tx = tid & 31, ty = tid >> 5;
        const int k0 = by * 32, n0 = bx * 32;
#pragma unroll
        for (int r = 0; r < 32; r += 8) tile[ty + r][tx] = W[(k0 + ty + r) * 512 + n0 + tx];
        __syncthreads();
#pragma unroll
        for (int r = 0; r < 32; r += 8) T[(n0 + ty + r) * 512 + k0 + tx] = f2bf(tile[tx][ty + r]);
    } else {
        int i = (bid - 13312) * 256 + tid;
        int m = mask[i];
        unsigned long long bal = __ballot(m != 0);
        if ((tid & 63) == 0) {
            uint2 w2; w2.x = (unsigned)bal; w2.y = (unsigned)(bal >> 32);
            *(uint2*)&bits[i >> 5] = w2;
        }
    }
}

// ---------- bf16 GEMM: C[m][n] = (sum_k A[m][k]*Bt[n][k] + bias) * scale ----------
// BN=64, BK=32, 4 waves as 2x2 (wave tile BM/2 x 32). BM in {64,128}.
// Blocks with blockIdx.y < ysplit use Bt0/bias0/scale0, else Bt1/bias1/scale1.
// NOTE: rows 64..127 of As start at u16 index 64*32 = 2048 (NOT 4096 — that
// off-by-2x overran As into Bs and read uninitialized LDS; rounds 3-5 NaN).
template <int BM, int BIAS_ROW, int OUT_F32>
__global__ __launch_bounds__(256, 4) void gemm_bt(
    const u16* __restrict__ A, const u16* __restrict__ Bt0, const u16* __restrict__ Bt1,
    const float* __restrict__ bias0, const float* __restrict__ bias1,
    void* __restrict__ Cout, int M, int N, int K, int ysplit,
    float scale0, float scale1) {
    constexpr int MR = BM / 32;
    const u16* Bt = (blockIdx.y < (unsigned)ysplit) ? Bt0 : Bt1;
    const float* bias = (blockIdx.y < (unsigned)ysplit) ? bias0 : bias1;
    const float scale = (blockIdx.y < (unsigned)ysplit) ? scale0 : scale1;
    __shared__ u16 As[BM * 32];
    __shared__ u16 Bs[64 * 32];
    const int t = threadIdx.x, l = t & 63, w = t >> 6;
    const int lr = l & 15, lg = l >> 4;
    const int m0 = blockIdx.y * BM, n0 = blockIdx.x * 64;
    const int wr = w >> 1, wc = w & 1;
    f32x4 acc[MR][2] = {};
    const int ar = t >> 2, ac = (t & 3) * 8;

    for (int kk = 0; kk < K; kk += 32) {
        __syncthreads();
        gload16(A + (m0 + ar) * K + kk + ac, As + w * 512);
        if (BM == 128)
            gload16(A + (m0 + 64 + ar) * K + kk + ac, As + 2048 + w * 512);
        gload16(Bt + (n0 + ar) * K + kk + ac, Bs + w * 512);
        __syncthreads();
        s16x8 af[MR], bfr[2];
#pragma unroll
        for (int m = 0; m < MR; ++m)
            af[m] = *(const s16x8*)&As[(wr * (BM / 2) + m * 16 + lr) * 32 + lg * 8];
#pragma unroll
        for (int n = 0; n < 2; ++n)
            bfr[n] = *(const s16x8*)&Bs[(wc * 32 + n * 16 + lr) * 32 + lg * 8];
#pragma unroll
        for (int m = 0; m < MR; ++m)
#pragma unroll
            for (int n = 0; n < 2; ++n) acc[m][n] = mfma16(af[m], bfr[n], acc[m][n]);
    }

#pragma unroll
    for (int n = 0; n < 2; ++n) {
        const int cg = n0 + wc * 32 + n * 16 + lr;
        const float bcol = BIAS_ROW ? 0.f : bias[cg];
#pragma unroll
        for (int m = 0; m < MR; ++m) {
            const int rbase = m0 + wr * (BM / 2) + m * 16 + lg * 4;
#pragma unroll
            for (int j = 0; j < 4; ++j) {
                const int rg = rbase + j;
                float val = (acc[m][n][j] + (BIAS_ROW ? bias[rg] : bcol)) * scale;
                if (OUT_F32) ((float*)Cout)[(size_t)rg * N + cg] = val;
                else         ((u16*)Cout)[(size_t)rg * N + cg] = f2bf(val);
            }
        }
    }
}

// ---------- flash attention ----------
// Grid (32 qtiles, 32 bh). 4 waves x 16 q-rows. KT=64 per iter.
// m=0 online softmax (scores O(5); masked -> exp2(-1e9)=0). Q pre-scaled by
// 0.125*log2(e) in the projection GEMM so native exp2 applies directly.
// Double-buffered K/V staging (T3 2-phase): stage(t+1) issued right after the
// single per-iter barrier, overlapping compute(t); the barrier's implicit
// vmcnt(0) drains it one iter later. Mask words prefetched one tile ahead in
// regs so their use never forces an early vmcnt drain. P round-trip via
// per-wave XOR-swizzled Ps (round-2-proven). l-sum deferred to epilogue.
__global__ __launch_bounds__(256, 4) void attn_fwd(
    const u16* __restrict__ Qp, const u16* __restrict__ Kp,
    const u16* __restrict__ Vt, const unsigned* __restrict__ mbits,
    u16* __restrict__ AO) {
    constexpr int S = 2048;
    const int qt = blockIdx.x, bh = blockIdx.y;
    const int b = bh >> 3, h = bh & 7;
    const int t = threadIdx.x, l = t & 63, w = t >> 6;
    const int lr = l & 15, lg = l >> 4;

    __shared__ u16 Ks[2][64 * 64];   // [buf][kt][d], XOR-swizzled chunks
    __shared__ u16 Vs[2][64 * 64];   // [buf][d][kt], XOR-swizzled chunks
    __shared__ u16 Ps[4][16 * 64];   // per-wave P [q][kt], XOR-swizzled

    const int q0 = qt * 64 + w * 16;
    const int bS = b * S;

    // Q fragments (already scaled by 0.125*log2(e) in the GEMM epilogue)
    s16x8 qf[2];
#pragma unroll
    for (int ks = 0; ks < 2; ++ks)
        qf[ks] = *(const s16x8*)&Qp[(bS + q0 + lr) * 512 + h * 64 + ks * 32 + lg * 8];

    f32x4 po[4] = {};
    float lrun[4] = {0.f, 0.f, 0.f, 0.f};

    // staging chunk assignment (inverse-XOR on global source -> swizzled LDS)
    const int kc0 = t, kc1 = 256 + t;
    const int krow0 = kc0 >> 3, kcol0 = ((kc0 & 7) ^ (krow0 & 7)) * 8;
    const int krow1 = kc1 >> 3, kcol1 = ((kc1 & 7) ^ (krow1 & 7)) * 8;

#define STAGE(nb, kt0)                                                              \
    do {                                                                            \
        gload16(&Kp[(bS + (kt0) + krow0) * 512 + h * 64 + kcol0], &Ks[nb][w * 512]);\
        gload16(&Kp[(bS + (kt0) + krow1) * 512 + h * 64 + kcol1], &Ks[nb][2048 + w * 512]);\
        gload16(&Vt[(h * 64 + krow0) * (4 * S) + bS + (kt0) + kcol0], &Vs[nb][w * 512]);\
        gload16(&Vt[(h * 64 + krow1) * (4 * S) + bS + (kt0) + kcol1], &Vs[nb][2048 + w * 512]);\
    } while (0)

    uint2 mw[4], mwn[4];
    STAGE(0, 0);
#pragma unroll
    for (int jj = 0; jj < 4; ++jj)
        mw[jj] = *(const uint2*)&mbits[(bS + q0 + lg * 4 + jj) * 64];
#pragma unroll
    for (int jj = 0; jj < 4; ++jj) mwn[jj] = mw[jj];

    for (int it = 0; it < 32; ++it) {
        const int cur = it & 1;
        // one barrier per iter: drains stage(it) (implicit vmcnt(0)) and
        // guards buf reuse (all reads of buf[cur] from iter it-2 are done)
        __syncthreads();
        if (it + 1 < 32) {
            STAGE(cur ^ 1, (it + 1) * 64);
#pragma unroll
            for (int jj = 0; jj < 4; ++jj)
                mwn[jj] = *(const uint2*)&mbits[(bS + q0 + lg * 4 + jj) * 64 + ((it + 1) << 1)];
        }
        const u16* Kc = Ks[cur];
        const u16* Vc = Vs[cur];

        // ---- QK^T ----
        f32x4 sc[4];
#pragma unroll
        for (int nk = 0; nk < 4; ++nk) sc[nk] = f32x4{0.f, 0.f, 0.f, 0.f};
        __builtin_amdgcn_s_setprio(1);
#pragma unroll
        for (int nk = 0; nk < 4; ++nk) {
            const int ktc = nk * 16 + lr;
            const int sw = (ktc & 7) << 4;
            s16x8 k0 = *(const s16x8*)((const char*)Kc + ((ktc * 128 + lg * 16) ^ sw));
            s16x8 k1 = *(const s16x8*)((const char*)Kc + ((ktc * 128 + 64 + lg * 16) ^ sw));
            sc[nk] = mfma16(qf[0], k0, sc[nk]);
            sc[nk] = mfma16(qf[1], k1, sc[nk]);
        }
        __builtin_amdgcn_s_setprio(0);

        // ---- mask + exp2 ----
#pragma unroll
        for (int nk = 0; nk < 4; ++nk) {
            const unsigned bp = ((nk & 1) << 4) + lr;
#pragma unroll
            for (int jj = 0; jj < 4; ++jj) {
                const unsigned word = (nk >> 1) ? mw[jj].y : mw[jj].x;
                const float s = ((word >> bp) & 1u) ? sc[nk][jj] : -1e9f;
                sc[nk][jj] = fexp2(s);
            }
        }
#pragma unroll
        for (int jj = 0; jj < 4; ++jj)
            lrun[jj] += (sc[0][jj] + sc[1][jj]) + (sc[2][jj] + sc[3][jj]);

        // ---- P write (wave-private, swizzled; hardware bf16 cvt) ----
#pragma unroll
        for (int nk = 0; nk < 4; ++nk) {
            const int ktc = nk * 16 + lr;
#pragma unroll
            for (int jj = 0; jj < 4; ++jj) {
                const int qloc = lg * 4 + jj;
                const int byte = (qloc * 128 + ktc * 2) ^ ((qloc & 7) << 4);
                *(u16*)((char*)&Ps[w][0] + byte) = f2bfh(sc[nk][jj]);
            }
        }

        // ---- PV A-fragments (swizzled b128 reads) ----
        s16x8 pa[2];
#pragma unroll
        for (int k2 = 0; k2 < 2; ++k2) {
            const int byte = (lr * 128 + k2 * 64 + lg * 16) ^ ((lr & 7) << 4);
            pa[k2] = *(const s16x8*)((const char*)&Ps[w][0] + byte);
        }

        // ---- PV ----
        __builtin_amdgcn_s_setprio(1);
#pragma unroll
        for (int dn = 0; dn < 4; ++dn) {
            const int d = dn * 16 + lr;
            const int sw = (d & 7) << 4;
            s16x8 v0 = *(const s16x8*)((const char*)Vc + ((d * 128 + lg * 16) ^ sw));
            s16x8 v1 = *(const s16x8*)((const char*)Vc + ((d * 128 + 64 + lg * 16) ^ sw));
            po[dn] = mfma16(pa[0], v0, po[dn]);
            po[dn] = mfma16(pa[1], v1, po[dn]);
        }
        __builtin_amdgcn_s_setprio(0);

#pragma unroll
        for (int jj = 0; jj < 4; ++jj) mw[jj] = mwn[jj];
    }
#undef STAGE

    // ---- epilogue: single l reduction + normalize + store ----
#pragma unroll
    for (int jj = 0; jj < 4; ++jj) {
        float s = lrun[jj];
        s += __shfl_xor(s, 1);
        s += __shfl_xor(s, 2);
        s += __shfl_xor(s, 4);
        s += __shfl_xor(s, 8);
        const float inv = 1.f / s;
        const int q = q0 + lg * 4 + jj;
#pragma unroll
        for (int dn = 0; dn < 4; ++dn)
            AO[(bS + q) * 512 + h * 64 + dn * 16 + lr] = f2bfh(po[dn][jj] * inv);
    }
}

// ---------- launcher ----------
extern "C" void kernel_launch(void* const* d_in, const int* in_sizes, int n_in,
                              void* d_out, int out_size, void* d_ws, size_t ws_size,
                              hipStream_t stream) {
    (void)in_sizes; (void)n_in; (void)out_size; (void)ws_size;
    const float* query = (const float*)d_in[0];
    const float* key   = (const float*)d_in[1];
    const float* value = (const float*)d_in[2];
    const int*   mask  = (const int*)d_in[3];
    const float* Wq = (const float*)d_in[4];
    const float* bq = (const float*)d_in[5];
    const float* Wk = (const float*)d_in[6];
    const float* bk = (const float*)d_in[7];
    const float* Wv = (const float*)d_in[8];
    const float* bv = (const float*)d_in[9];
    const float* Wo = (const float*)d_in[10];
    const float* bo = (const float*)d_in[11];

    char* ws = (char*)d_ws;
    const size_t MB = 1ull << 20;
    u16* qb  = (u16*)(ws);                       // 24 MB: qb|kb|vb contiguous
    u16* vb  = (u16*)(ws + 16 * MB);
    u16* WqT = (u16*)(ws + 24 * MB);
    u16* WkT = (u16*)(ws + 24 * MB + 512 * 1024);
    u16* WvT = (u16*)(ws + 25 * MB);
    u16* WoT = (u16*)(ws + 25 * MB + 512 * 1024);
    unsigned* mb = (unsigned*)(ws + 26 * MB);    // 2 MB
    u16* Qp = (u16*)(ws + 28 * MB);              // Qp|Kp contiguous 16 MB
    u16* Vt = (u16*)(ws + 44 * MB);              // [512][8192]
    u16* AO = (u16*)(ws + 52 * MB);              // end: 60 MB

    prep<<<78848, 256, 0, stream>>>((const float4*)query, (const float4*)key,
                                    (const float4*)value, (u16x4*)qb,
                                    Wq, Wk, Wv, Wo, WqT, WkT, WvT, WoT, mask, mb);

    // Q and K projections fused: rows 0..8191 -> Wq (pre-scaled by
    // 0.125*log2(e) for the exp2 softmax), rows 8192..16383 -> Wk
    gemm_bt<128, 0, 0><<<dim3(8, 128), 256, 0, stream>>>(
        qb, WqT, WkT, bq, bk, Qp, 16384, 512, 512, 64, 0.18033688f, 1.0f);
    // V projection transposed: C[d][s] = (Wv^T)[d][:] . Xv[s][:] + bv[d] = Vproj^T
    gemm_bt<64, 1, 0><<<dim3(128, 8), 256, 0, stream>>>(
        WvT, vb, vb, bv, bv, Vt, 512, 8192, 512, 999, 1.0f, 1.0f);

    attn_fwd<<<dim3(32, 32), 256, 0, stream>>>(Qp, Qp + 8192 * 512, Vt, mb, AO);

    // output projection -> fp32 d_out
    gemm_bt<64, 0, 1><<<dim3(8, 128), 256, 0, stream>>>(
        AO, WoT, WoT, bo, bo, (float*)d_out, 8192, 512, 512, 999, 1.0f, 1.0f);
}

// Round 9
// 150.663 us; speedup vs baseline: 1.0422x; 1.0422x over previous
//
#include <hip/hip_runtime.h>
#include <hip/hip_bf16.h>

typedef unsigned short u16;
typedef __attribute__((ext_vector_type(4))) float f32x4;
typedef __attribute__((ext_vector_type(16))) float f32x16;
typedef __attribute__((ext_vector_type(8))) short s16x8;
typedef __attribute__((ext_vector_type(4))) unsigned short u16x4;

// ---------- helpers ----------
__device__ __forceinline__ u16 f2bf(float f) {
    union { float f; unsigned u; } v; v.f = f;
    unsigned r = v.u + 0x7fffu + ((v.u >> 16) & 1u);  // RNE (software)
    return (u16)(r >> 16);
}
__device__ __forceinline__ u16 f2bfh(float f) {   // hardware cvt via compiler
    __hip_bfloat16 h = __float2bfloat16(f);
    return *reinterpret_cast<u16*>(&h);
}
__device__ __forceinline__ float fexp2(float x) {
#if __has_builtin(__builtin_amdgcn_exp2f)
    return __builtin_amdgcn_exp2f(x);
#else
    return exp2f(x);
#endif
}
__device__ __forceinline__ void gload16(const void* g, void* lds_uniform) {
    __builtin_amdgcn_global_load_lds(
        (const __attribute__((address_space(1))) void*)g,
        (__attribute__((address_space(3))) void*)lds_uniform, 16, 0, 0);
}
__device__ __forceinline__ f32x4 mfma16(s16x8 a, s16x8 b, f32x4 c) {
    return __builtin_amdgcn_mfma_f32_16x16x32_bf16(a, b, c, 0, 0, 0);
}
__device__ __forceinline__ f32x16 mfma32(s16x8 a, s16x8 b, f32x16 c) {
    return __builtin_amdgcn_mfma_f32_32x32x16_bf16(a, b, c, 0, 0, 0);
}

// ---------- fused prep: cvt(q,k,v)->bf16 | weight transpose | mask packing ----------
// blocks [0,12288): convert; [12288,13312): wtrans; [13312,78848): packmask
__global__ void prep(const float4* __restrict__ q, const float4* __restrict__ k,
                     const float4* __restrict__ v, u16x4* __restrict__ qkv,
                     const float* __restrict__ Wq, const float* __restrict__ Wk,
                     const float* __restrict__ Wv, const float* __restrict__ Wo,
                     u16* __restrict__ WqT, u16* __restrict__ WkT,
                     u16* __restrict__ WvT, u16* __restrict__ WoT,
                     const int* __restrict__ mask, unsigned* __restrict__ bits) {
    __shared__ float tile[32][33];
    const int bid = blockIdx.x, tid = threadIdx.x;
    if (bid < 12288) {
        int i = bid * 256 + tid;               // 0 .. 3*2^20-1
        int sel = i >> 20, j = i & 0xFFFFF;
        const float4* in = (sel == 0) ? q : (sel == 1) ? k : v;
        float4 f = in[j];
        u16x4 o;
        o[0] = f2bf(f.x); o[1] = f2bf(f.y); o[2] = f2bf(f.z); o[3] = f2bf(f.w);
        qkv[i] = o;
    } else if (bid < 13312) {
        int idx = bid - 12288;
        int bz = idx >> 8, rem = idx & 255, by = rem >> 4, bx = rem & 15;
        const float* W; u16* T;
        switch (bz) {
            case 0: W = Wq; T = WqT; break;
            case 1: W = Wk; T = WkT; break;
            case 2: W = Wv; T = WvT; break;
            default: W = Wo; T = WoT; break;
        }
        const int tx = tid & 31, ty = tid >> 5;
        const int k0 = by * 32, n0 = bx * 32;
#pragma unroll
        for (int r = 0; r < 32; r += 8) tile[ty + r][tx] = W[(k0 + ty + r) * 512 + n0 + tx];
        __syncthreads();
#pragma unroll
        for (int r = 0; r < 32; r += 8) T[(n0 + ty + r) * 512 + k0 + tx] = f2bf(tile[tx][ty + r]);
    } else {
        int i = (bid - 13312) * 256 + tid;
        int m = mask[i];
        unsigned long long bal = __ballot(m != 0);
        if ((tid & 63) == 0) {
            uint2 w2; w2.x = (unsigned)bal; w2.y = (unsigned)(bal >> 32);
            *(uint2*)&bits[i >> 5] = w2;
        }
    }
}

// ---------- bf16 GEMM: C[m][n] = (sum_k A[m][k]*Bt[n][k] + bias) * scale ----------
// BN=64, BK=32, 4 waves as 2x2 (wave tile BM/2 x 32). BM in {64,128}.
// Blocks with blockIdx.y < ysplit use Bt0/bias0/scale0, else Bt1/bias1/scale1.
// NOTE: rows 64..127 of As start at u16 index 64*32 = 2048 (NOT 4096 — that
// off-by-2x overran As into Bs and read uninitialized LDS; rounds 3-5 NaN).
template <int BM, int BIAS_ROW, int OUT_F32>
__global__ __launch_bounds__(256, 4) void gemm_bt(
    const u16* __restrict__ A, const u16* __restrict__ Bt0, const u16* __restrict__ Bt1,
    const float* __restrict__ bias0, const float* __restrict__ bias1,
    void* __restrict__ Cout, int M, int N, int K, int ysplit,
    float scale0, float scale1) {
    constexpr int MR = BM / 32;
    const u16* Bt = (blockIdx.y < (unsigned)ysplit) ? Bt0 : Bt1;
    const float* bias = (blockIdx.y < (unsigned)ysplit) ? bias0 : bias1;
    const float scale = (blockIdx.y < (unsigned)ysplit) ? scale0 : scale1;
    __shared__ u16 As[BM * 32];
    __shared__ u16 Bs[64 * 32];
    const int t = threadIdx.x, l = t & 63, w = t >> 6;
    const int lr = l & 15, lg = l >> 4;
    const int m0 = blockIdx.y * BM, n0 = blockIdx.x * 64;
    const int wr = w >> 1, wc = w & 1;
    f32x4 acc[MR][2] = {};
    const int ar = t >> 2, ac = (t & 3) * 8;

    for (int kk = 0; kk < K; kk += 32) {
        __syncthreads();
        gload16(A + (m0 + ar) * K + kk + ac, As + w * 512);
        if (BM == 128)
            gload16(A + (m0 + 64 + ar) * K + kk + ac, As + 2048 + w * 512);
        gload16(Bt + (n0 + ar) * K + kk + ac, Bs + w * 512);
        __syncthreads();
        s16x8 af[MR], bfr[2];
#pragma unroll
        for (int m = 0; m < MR; ++m)
            af[m] = *(const s16x8*)&As[(wr * (BM / 2) + m * 16 + lr) * 32 + lg * 8];
#pragma unroll
        for (int n = 0; n < 2; ++n)
            bfr[n] = *(const s16x8*)&Bs[(wc * 32 + n * 16 + lr) * 32 + lg * 8];
#pragma unroll
        for (int m = 0; m < MR; ++m)
#pragma unroll
            for (int n = 0; n < 2; ++n) acc[m][n] = mfma16(af[m], bfr[n], acc[m][n]);
    }

#pragma unroll
    for (int n = 0; n < 2; ++n) {
        const int cg = n0 + wc * 32 + n * 16 + lr;
        const float bcol = BIAS_ROW ? 0.f : bias[cg];
#pragma unroll
        for (int m = 0; m < MR; ++m) {
            const int rbase = m0 + wr * (BM / 2) + m * 16 + lg * 4;
#pragma unroll
            for (int j = 0; j < 4; ++j) {
                const int rg = rbase + j;
                float val = (acc[m][n][j] + (BIAS_ROW ? bias[rg] : bcol)) * scale;
                if (OUT_F32) ((float*)Cout)[(size_t)rg * N + cg] = val;
                else         ((u16*)Cout)[(size_t)rg * N + cg] = f2bf(val);
            }
        }
    }
}

// ---------- flash attention (32x32 MFMA, P fully in registers) ----------
// Grid (16 qtiles, 32 bh), 4 waves x 32 q-rows, KVBLK=64.
// Swapped QK^T: C[kt][q] = sum_d K[kt][d] * Q[q][d] via mfma32(A=K, B=Q).
// C-layout (m74/m101): col=lane&31 -> q lane-local; rows kt=(r&3)+8*(r>>2)+4*hi.
// Softmax per lane (one q): mask bit (w32>>(shift+4*hi))&1, exp2 (Q pre-scaled
// by 0.125*log2e in the projection GEMM), lane-local running sum.
// P -> PV B-operand IN REGISTERS (T12): v_cvt_pk_bf16_f32 row-pairs, then
// v_permlane32_swap_b32 (pk0<->pk2, pk1<->pk3) makes each lane hold the
// kt-contiguous 8-run its B-fragment slot needs. PV: out^T[d][q] =
// sum V^T[d][kt] P^T[kt][q], A=V^T straight from the Vt-layout LDS tile.
// LDS traffic/wave-iter: 16 ds_read_b128, zero P round-trip (was 26 ops).
__global__ __launch_bounds__(256, 2) void attn_fwd(
    const u16* __restrict__ Qp, const u16* __restrict__ Kp,
    const u16* __restrict__ Vt, const unsigned* __restrict__ mbits,
    u16* __restrict__ AO) {
    constexpr int S = 2048;
    const int qt = blockIdx.x, bh = blockIdx.y;
    const int b = bh >> 3, h = bh & 7;
    const int t = threadIdx.x, l = t & 63, w = t >> 6;
    const int lq = l & 31, hi = l >> 5;
    const int hi8 = hi * 8, hi4 = hi * 4;

    __shared__ u16 Ks[2][64 * 64];   // [buf][kt][d], XOR-swizzled chunks
    __shared__ u16 Vs[2][64 * 64];   // [buf][d][kt], XOR-swizzled chunks

    const int q0w = qt * 128 + w * 32;
    const int bS = b * S;

    // Q as PV-B-style fragments: lane holds Q[q=lq][d = ds*16 + hi8 + j]
    s16x8 qf[4];
#pragma unroll
    for (int ds = 0; ds < 4; ++ds)
        qf[ds] = *(const s16x8*)&Qp[(bS + q0w + lq) * 512 + h * 64 + ds * 16 + hi8];

    f32x16 po[2];
#pragma unroll
    for (int r = 0; r < 16; ++r) { po[0][r] = 0.f; po[1][r] = 0.f; }
    float lrun = 0.f;

    // staging chunk assignment (inverse-XOR on global source -> swizzled LDS)
    const int kc0 = t, kc1 = 256 + t;
    const int krow0 = kc0 >> 3, kcol0 = ((kc0 & 7) ^ (krow0 & 7)) * 8;
    const int krow1 = kc1 >> 3, kcol1 = ((kc1 & 7) ^ (krow1 & 7)) * 8;

#define STAGE(nb, kt0)                                                              \
    do {                                                                            \
        gload16(&Kp[(bS + (kt0) + krow0) * 512 + h * 64 + kcol0], &Ks[nb][w * 512]);\
        gload16(&Kp[(bS + (kt0) + krow1) * 512 + h * 64 + kcol1], &Ks[nb][2048 + w * 512]);\
        gload16(&Vt[(h * 64 + krow0) * (4 * S) + bS + (kt0) + kcol0], &Vs[nb][w * 512]);\
        gload16(&Vt[(h * 64 + krow1) * (4 * S) + bS + (kt0) + kcol1], &Vs[nb][2048 + w * 512]);\
    } while (0)

    STAGE(0, 0);
    uint2 mwv = *(const uint2*)&mbits[(bS + q0w + lq) * 64];
    uint2 mwn = mwv;

    for (int it = 0; it < 32; ++it) {
        const int cur = it & 1;
        // single barrier/iter: implicit vmcnt(0) drains stage(it) and fences
        // buf reuse across the double buffer
        __syncthreads();
        if (it + 1 < 32) {
            STAGE(cur ^ 1, (it + 1) * 64);
            mwn = *(const uint2*)&mbits[(bS + q0w + lq) * 64 + ((it + 1) << 1)];
        }
        const u16* Kc = Ks[cur];
        const u16* Vc = Vs[cur];

        // ---- QK^T + softmax + in-register P repack, per 32-kt tile ----
        s16x8 bq[4];
#pragma unroll
        for (int kt_t = 0; kt_t < 2; ++kt_t) {
            f32x16 sc;
#pragma unroll
            for (int r = 0; r < 16; ++r) sc[r] = 0.f;
            __builtin_amdgcn_s_setprio(1);
#pragma unroll
            for (int ds = 0; ds < 4; ++ds) {
                const int row = kt_t * 32 + lq;
                const int byte = (row * 128 + ds * 32 + hi * 16) ^ ((row & 7) << 4);
                s16x8 ka = *(const s16x8*)((const char*)Kc + byte);
                sc = mfma32(ka, qf[ds], sc);
            }
            __builtin_amdgcn_s_setprio(0);

            const unsigned w32 = kt_t ? mwv.y : mwv.x;
            float p[16];
            float ps = 0.f;
#pragma unroll
            for (int r = 0; r < 16; ++r) {
                const int shift = (r & 3) + 8 * (r >> 2);   // + hi4 at runtime
                const float s = ((w32 >> (shift + hi4)) & 1u) ? sc[r] : -1e9f;
                p[r] = fexp2(s);
                ps += p[r];
            }
            lrun += ps;

            // pack row-pairs to bf16; swap halves so each lane owns its 8-run
            unsigned pk[8];
#pragma unroll
            for (int i = 0; i < 8; ++i) {
                unsigned v;
                asm("v_cvt_pk_bf16_f32 %0, %1, %2"
                    : "=v"(v) : "v"(p[2 * i]), "v"(p[2 * i + 1]));
                pk[i] = v;
            }
            asm("v_permlane32_swap_b32 %0, %1" : "+v"(pk[0]), "+v"(pk[2]));
            asm("v_permlane32_swap_b32 %0, %1" : "+v"(pk[1]), "+v"(pk[3]));
            asm("v_permlane32_swap_b32 %0, %1" : "+v"(pk[4]), "+v"(pk[6]));
            asm("v_permlane32_swap_b32 %0, %1" : "+v"(pk[5]), "+v"(pk[7]));
            union BQ { unsigned u[4]; s16x8 v; } b0, b1;
            b0.u[0] = pk[0]; b0.u[1] = pk[1]; b0.u[2] = pk[2]; b0.u[3] = pk[3];
            b1.u[0] = pk[4]; b1.u[1] = pk[5]; b1.u[2] = pk[6]; b1.u[3] = pk[7];
            bq[kt_t * 2]     = b0.v;   // kt-slice [32*kt_t,      +16)
            bq[kt_t * 2 + 1] = b1.v;   // kt-slice [32*kt_t + 16, +16)
        }

        // ---- PV: out^T[d][q] += V^T-slice * P^T-slice ----
        __builtin_amdgcn_s_setprio(1);
#pragma unroll
        for (int dt = 0; dt < 2; ++dt)
#pragma unroll
            for (int ks = 0; ks < 4; ++ks) {
                const int row = dt * 32 + lq;
                const int byte = (row * 128 + ks * 32 + hi * 16) ^ ((row & 7) << 4);
                s16x8 va = *(const s16x8*)((const char*)Vc + byte);
                po[dt] = mfma32(va, bq[ks], po[dt]);
            }
        __builtin_amdgcn_s_setprio(0);

        mwv = mwn;
    }
#undef STAGE

    // ---- epilogue: cross-half l sum, normalize, paired bf16 stores ----
    lrun += __shfl_xor(lrun, 32);
    const float inv = 1.f / lrun;
    const int orow = (bS + q0w + lq) * 512 + h * 64;
#pragma unroll
    for (int dt = 0; dt < 2; ++dt)
#pragma unroll
        for (int r = 0; r < 16; r += 2) {
            const int d = dt * 32 + (r & 3) + 8 * (r >> 2) + hi4;
            const unsigned lo = f2bfh(po[dt][r] * inv);
            const unsigned hh = f2bfh(po[dt][r + 1] * inv);
            *(unsigned*)&AO[orow + d] = lo | (hh << 16);
        }
}

// ---------- launcher ----------
extern "C" void kernel_launch(void* const* d_in, const int* in_sizes, int n_in,
                              void* d_out, int out_size, void* d_ws, size_t ws_size,
                              hipStream_t stream) {
    (void)in_sizes; (void)n_in; (void)out_size; (void)ws_size;
    const float* query = (const float*)d_in[0];
    const float* key   = (const float*)d_in[1];
    const float* value = (const float*)d_in[2];
    const int*   mask  = (const int*)d_in[3];
    const float* Wq = (const float*)d_in[4];
    const float* bq = (const float*)d_in[5];
    const float* Wk = (const float*)d_in[6];
    const float* bk = (const float*)d_in[7];
    const float* Wv = (const float*)d_in[8];
    const float* bv = (const float*)d_in[9];
    const float* Wo = (const float*)d_in[10];
    const float* bo = (const float*)d_in[11];

    char* ws = (char*)d_ws;
    const size_t MB = 1ull << 20;
    u16* qb  = (u16*)(ws);                       // 24 MB: qb|kb|vb contiguous
    u16* vb  = (u16*)(ws + 16 * MB);
    u16* WqT = (u16*)(ws + 24 * MB);
    u16* WkT = (u16*)(ws + 24 * MB + 512 * 1024);
    u16* WvT = (u16*)(ws + 25 * MB);
    u16* WoT = (u16*)(ws + 25 * MB + 512 * 1024);
    unsigned* mb = (unsigned*)(ws + 26 * MB);    // 2 MB
    u16* Qp = (u16*)(ws + 28 * MB);              // Qp|Kp contiguous 16 MB
    u16* Vt = (u16*)(ws + 44 * MB);              // [512][8192]
    u16* AO = (u16*)(ws + 52 * MB);              // end: 60 MB

    prep<<<78848, 256, 0, stream>>>((const float4*)query, (const float4*)key,
                                    (const float4*)value, (u16x4*)qb,
                                    Wq, Wk, Wv, Wo, WqT, WkT, WvT, WoT, mask, mb);

    // Q and K projections fused: rows 0..8191 -> Wq (pre-scaled by
    // 0.125*log2(e) for the exp2 softmax), rows 8192..16383 -> Wk
    gemm_bt<128, 0, 0><<<dim3(8, 128), 256, 0, stream>>>(
        qb, WqT, WkT, bq, bk, Qp, 16384, 512, 512, 64, 0.18033688f, 1.0f);
    // V projection transposed: C[d][s] = (Wv^T)[d][:] . Xv[s][:] + bv[d] = Vproj^T
    gemm_bt<64, 1, 0><<<dim3(128, 8), 256, 0, stream>>>(
        WvT, vb, vb, bv, bv, Vt, 512, 8192, 512, 999, 1.0f, 1.0f);

    attn_fwd<<<dim3(16, 32), 256, 0, stream>>>(Qp, Qp + 8192 * 512, Vt, mb, AO);

    // output projection -> fp32 d_out
    gemm_bt<64, 0, 1><<<dim3(8, 128), 256, 0, stream>>>(
        AO, WoT, WoT, bo, bo, (float*)d_out, 8192, 512, 512, 999, 1.0f, 1.0f);
}